// Round 1
// baseline (263.388 us; speedup 1.0000x reference)
//
#include <hip/hip_runtime.h>
#include <stdint.h>

#define NPTS        16384
#define BATCH       8
#define QPB         128                     // queries per block (4 waves * 32)
#define QBLKS       (NPTS / QPB)            // 128
#define CHAM_BLOCKS (BATCH * 2 * QBLKS)     // 2048
#define NOISE_N     (BATCH * NPTS * 3)      // 393216
#define NOISE_V4    (NOISE_N / 4)           // 98304
#define NPTS_TOT    (BATCH * NPTS)          // 131072
#define PACK_BLOCKS (NPTS_TOT / 256)        // 512
#define REF_ITERS   (NPTS * 8 / 1024)       // 128 (1 KB of packed refs per iter)

// workspace layout (bytes)
#define WS_NOISE_PART 0                     // 512 floats
#define WS_CHAM_PART  4096                  // 2048 floats
#define WS_PK_PRED    16384
#define WS_PK_TARG    (WS_PK_PRED + 8 * NPTS_TOT)
#define WS_R_PRED     (WS_PK_TARG + 8 * NPTS_TOT)
#define WS_R_TARG     (WS_R_PRED + 4 * NPTS_TOT)

using halfx8 = __attribute__((ext_vector_type(8))) _Float16;
using f32x16 = __attribute__((ext_vector_type(16))) float;
using intx4  = __attribute__((ext_vector_type(4))) int;

__device__ __forceinline__ unsigned int f2h(float f) {
  union { _Float16 h; unsigned short s; } v; v.h = (_Float16)f; return v.s;
}
__device__ __forceinline__ float h2f(unsigned short s) {
  union { _Float16 h; unsigned short u; } v; v.u = s; return (float)v.h;
}
__device__ __forceinline__ float min3(float a, float b, float c) {
  return fminf(fminf(a, b), c);   // pattern-matched to v_min3_f32
}

// ---------------- fused pack (f32 xyz -> f16 {x,y,z,s} + f32 r) + noise L1 ----------------
__global__ void pack_noise_kernel(const float* __restrict__ pred,
                                  const float* __restrict__ targ,
                                  const float4* __restrict__ na,
                                  const float4* __restrict__ nb,
                                  ushort4* __restrict__ pk_pred,
                                  ushort4* __restrict__ pk_targ,
                                  float* __restrict__ r_pred,
                                  float* __restrict__ r_targ,
                                  float* __restrict__ part) {
  int i = blockIdx.x * 256 + threadIdx.x;
  {
    float x = pred[3*i+0], y = pred[3*i+1], z = pred[3*i+2];
    float s = __builtin_fmaf(x, x, __builtin_fmaf(y, y, z*z));
    pk_pred[i] = make_ushort4((unsigned short)f2h(x), (unsigned short)f2h(y),
                              (unsigned short)f2h(z), (unsigned short)f2h(s));
    r_pred[i] = s;
  }
  {
    float x = targ[3*i+0], y = targ[3*i+1], z = targ[3*i+2];
    float s = __builtin_fmaf(x, x, __builtin_fmaf(y, y, z*z));
    pk_targ[i] = make_ushort4((unsigned short)f2h(x), (unsigned short)f2h(y),
                              (unsigned short)f2h(z), (unsigned short)f2h(s));
    r_targ[i] = s;
  }
  // noise L1 over float4-packed elements (98304 of them < 131072 threads)
  float sn = 0.f;
  if (i < NOISE_V4) {
    float4 pa = na[i], pb = nb[i];
    sn = fabsf(pa.x-pb.x) + fabsf(pa.y-pb.y) + fabsf(pa.z-pb.z) + fabsf(pa.w-pb.w);
  }
  for (int o = 1; o < 64; o <<= 1) sn += __shfl_xor(sn, o);
  __shared__ float ws4[4];
  int lane = threadIdx.x & 63, wv = threadIdx.x >> 6;
  if (lane == 0) ws4[wv] = sn;
  __syncthreads();
  if (threadIdx.x == 0) part[blockIdx.x] = ws4[0] + ws4[1] + ws4[2] + ws4[3];
}

// ---------------- chamfer main kernel (no LDS staging: refs are L2-resident) ----------------
__global__ __launch_bounds__(256, 4)
void chamfer_kernel(const ushort4* __restrict__ pk_pred,
                    const ushort4* __restrict__ pk_targ,
                    const float* __restrict__ r_pred,
                    const float* __restrict__ r_targ,
                    float* __restrict__ part) {
  __shared__ float wsum[4];

  const int tid  = threadIdx.x;
  const int lane = tid & 63;
  const int wv   = tid >> 6;
  const int col  = lane & 31;

  const int blk  = blockIdx.x;
  const int qblk = blk & (QBLKS - 1);
  const int bd   = blk >> 7;
  const int dir  = bd & 1;
  const int b    = bd >> 1;

  const ushort4* qpk = dir ? pk_targ : pk_pred;
  const float*   qr  = dir ? r_targ  : r_pred;
  const ushort4* ref = dir ? pk_pred : pk_targ;
  qpk += b * NPTS; qr += b * NPTS; ref += b * NPTS;

  // ---- 4 B fragments (queries), built once. B[k][n]: lane l holds
  // k = 8*(l>>5) + e (e=0..7, reg r packs e=2r,2r+1), n = l&31.
  // Variant v is nonzero only at k = 4v..4v+3 = the query [-2x,-2y,-2z,1].
  const int q = qblk * QPB + wv * 32 + col;
  ushort4 qt = qpk[q];                       // both halves load their column's query
  unsigned int nx = f2h(-2.f * h2f(qt.x));
  unsigned int ny = f2h(-2.f * h2f(qt.y));
  unsigned int nz = f2h(-2.f * h2f(qt.z));
  unsigned int lo = (ny << 16) | nx;
  unsigned int hi = (0x3C00u << 16) | nz;    // [nz, 1.0f16]
  const bool hh = (lane >= 32);

  union BF { halfx8 v; unsigned int u[4]; };
  BF fb0, fb1, fb2, fb3;
  fb0.u[0] = hh ? 0u : lo; fb0.u[1] = hh ? 0u : hi; fb0.u[2] = 0u;           fb0.u[3] = 0u;
  fb1.u[0] = 0u;           fb1.u[1] = 0u;           fb1.u[2] = hh ? 0u : lo; fb1.u[3] = hh ? 0u : hi;
  fb2.u[0] = hh ? lo : 0u; fb2.u[1] = hh ? hi : 0u; fb2.u[2] = 0u;           fb2.u[3] = 0u;
  fb3.u[0] = 0u;           fb3.u[1] = 0u;           fb3.u[2] = hh ? lo : 0u; fb3.u[3] = hh ? hi : 0u;

  f32x16 czero = {0.f,0.f,0.f,0.f, 0.f,0.f,0.f,0.f, 0.f,0.f,0.f,0.f, 0.f,0.f,0.f,0.f};

  union AF { intx4 i; halfx8 h; };

  // Flat loop over all 16384 refs of this (b,dir): 128 iterations, each a
  // fully-coalesced 1 KB/wave global_load_dwordx4 straight from L2.
  // Lane L holds refs (64*it... specifically 128*(it&3)+... preserved layout:
  // iter it covers refs [it*128/..], lane L -> refs (2L, 2L+1) of that 1 KB
  // line; the 4 B variants select ref sets {2m}, {2m+1}, {64+2m}, {64+2m+1}.
  const char* rbase = (const char*)ref + lane * 16;
  float m = 1e30f;
#pragma unroll 4
  for (int it = 0; it < REF_ITERS; ++it) {
    AF fa;
    fa.i = *(const intx4*)(rbase + (size_t)it * 1024);
    f32x16 d0 = __builtin_amdgcn_mfma_f32_32x32x16_f16(fa.h, fb0.v, czero, 0, 0, 0);
    f32x16 d1 = __builtin_amdgcn_mfma_f32_32x32x16_f16(fa.h, fb1.v, czero, 0, 0, 0);
    f32x16 d2 = __builtin_amdgcn_mfma_f32_32x32x16_f16(fa.h, fb2.v, czero, 0, 0, 0);
    f32x16 d3 = __builtin_amdgcn_mfma_f32_32x32x16_f16(fa.h, fb3.v, czero, 0, 0, 0);
#pragma unroll
    for (int r = 0; r < 4; ++r) {
      const f32x16& d = (r == 0) ? d0 : (r == 1) ? d1 : (r == 2) ? d2 : d3;
      float t0 = min3(d[0],  d[1],  d[2]);
      float t1 = min3(d[3],  d[4],  d[5]);
      float t2 = min3(d[6],  d[7],  d[8]);
      float t3 = min3(d[9],  d[10], d[11]);
      float t4 = min3(d[12], d[13], d[14]);
      float u0 = min3(t0, t1, t2);
      float u1 = min3(t3, t4, d[15]);
      m = min3(m, u0, u1);
    }
  }

  // lanes l and l^32 cover complementary rows for the same query column
  m = fminf(m, __shfl_xor(m, 32));
  float rq = qr[q];
  float dmin = fmaxf(rq + m, 0.f);
  float v = (lane < 32) ? dmin : 0.f;
  for (int o = 1; o < 32; o <<= 1) v += __shfl_xor(v, o);
  if (lane == 0) wsum[wv] = v;
  __syncthreads();
  if (tid == 0) part[blockIdx.x] = wsum[0] + wsum[1] + wsum[2] + wsum[3];
}

// ---------------- final reduce ----------------
__global__ void final_kernel(const float* __restrict__ part_noise,
                             const float* __restrict__ part_cham,
                             float* __restrict__ out) {
  __shared__ float red[256];
  float s = 0.f;
  for (int i = threadIdx.x; i < PACK_BLOCKS; i += 256) s += part_noise[i];
  float t = 0.f;
  for (int i = threadIdx.x; i < CHAM_BLOCKS; i += 256) t += part_cham[i];
  red[threadIdx.x] = s; __syncthreads();
  for (int o = 128; o; o >>= 1) { if (threadIdx.x < o) red[threadIdx.x] += red[threadIdx.x + o]; __syncthreads(); }
  float noise_sum = red[0];
  __syncthreads();
  red[threadIdx.x] = t; __syncthreads();
  for (int o = 128; o; o >>= 1) { if (threadIdx.x < o) red[threadIdx.x] += red[threadIdx.x + o]; __syncthreads(); }
  if (threadIdx.x == 0)
    out[0] = noise_sum * (1.f / NOISE_N) + 0.1f * red[0] * (1.f / NPTS_TOT);
}

extern "C" void kernel_launch(void* const* d_in, const int* in_sizes, int n_in,
                              void* d_out, int out_size, void* d_ws, size_t ws_size,
                              hipStream_t stream) {
  const float* pn = (const float*)d_in[0];
  const float* an = (const float*)d_in[1];
  const float* pp = (const float*)d_in[2];
  const float* tp = (const float*)d_in[3];

  char* ws = (char*)d_ws;
  float*   noise_part = (float*)(ws + WS_NOISE_PART);
  float*   cham_part  = (float*)(ws + WS_CHAM_PART);
  ushort4* pk_pred    = (ushort4*)(ws + WS_PK_PRED);
  ushort4* pk_targ    = (ushort4*)(ws + WS_PK_TARG);
  float*   r_pred     = (float*)(ws + WS_R_PRED);
  float*   r_targ     = (float*)(ws + WS_R_TARG);

  pack_noise_kernel<<<PACK_BLOCKS, 256, 0, stream>>>(pp, tp, (const float4*)pn, (const float4*)an,
                                                     pk_pred, pk_targ, r_pred, r_targ, noise_part);
  chamfer_kernel<<<CHAM_BLOCKS, 256, 0, stream>>>(pk_pred, pk_targ, r_pred, r_targ, cham_part);
  final_kernel<<<1, 256, 0, stream>>>(noise_part, cham_part, (float*)d_out);
}

// Round 2
// 179.357 us; speedup vs baseline: 1.4685x; 1.4685x over previous
//
#include <hip/hip_runtime.h>
#include <stdint.h>

#define NPTS        16384
#define BATCH       8
#define QPB         128                     // queries per block (4 waves * 32)
#define QBLKS       (NPTS / QPB)            // 128
#define CHAM_BLOCKS (BATCH * 2 * QBLKS)     // 2048
#define NOISE_N     (BATCH * NPTS * 3)      // 393216
#define NOISE_V4    (NOISE_N / 4)           // 98304
#define NPTS_TOT    (BATCH * NPTS)          // 131072
#define PACK_BLOCKS (NPTS_TOT / 256)        // 512
#define REF_ITERS   (NPTS * 8 / 1024)       // 128 (1 KB of packed refs per iter)

// workspace layout (bytes)
#define WS_NOISE_PART 0                     // 512 floats
#define WS_CHAM_PART  4096                  // 2048 floats
#define WS_PK_PRED    16384
#define WS_PK_TARG    (WS_PK_PRED + 8 * NPTS_TOT)
#define WS_R_PRED     (WS_PK_TARG + 8 * NPTS_TOT)
#define WS_R_TARG     (WS_R_PRED + 4 * NPTS_TOT)

using halfx8 = __attribute__((ext_vector_type(8))) _Float16;
using f32x16 = __attribute__((ext_vector_type(16))) float;
using intx4  = __attribute__((ext_vector_type(4))) int;

__device__ __forceinline__ unsigned int f2h(float f) {
  union { _Float16 h; unsigned short s; } v; v.h = (_Float16)f; return v.s;
}
__device__ __forceinline__ float h2f(unsigned short s) {
  union { _Float16 h; unsigned short u; } v; v.u = s; return (float)v.h;
}
__device__ __forceinline__ float min3(float a, float b, float c) {
  return fminf(fminf(a, b), c);   // pattern-matched to v_min3_f32
}

// ---------------- fused pack (f32 xyz -> f16 {x,y,z,s} + f32 r) + noise L1 ----------------
__global__ void pack_noise_kernel(const float* __restrict__ pred,
                                  const float* __restrict__ targ,
                                  const float4* __restrict__ na,
                                  const float4* __restrict__ nb,
                                  ushort4* __restrict__ pk_pred,
                                  ushort4* __restrict__ pk_targ,
                                  float* __restrict__ r_pred,
                                  float* __restrict__ r_targ,
                                  float* __restrict__ part) {
  int i = blockIdx.x * 256 + threadIdx.x;
  {
    float x = pred[3*i+0], y = pred[3*i+1], z = pred[3*i+2];
    float s = __builtin_fmaf(x, x, __builtin_fmaf(y, y, z*z));
    pk_pred[i] = make_ushort4((unsigned short)f2h(x), (unsigned short)f2h(y),
                              (unsigned short)f2h(z), (unsigned short)f2h(s));
    r_pred[i] = s;
  }
  {
    float x = targ[3*i+0], y = targ[3*i+1], z = targ[3*i+2];
    float s = __builtin_fmaf(x, x, __builtin_fmaf(y, y, z*z));
    pk_targ[i] = make_ushort4((unsigned short)f2h(x), (unsigned short)f2h(y),
                              (unsigned short)f2h(z), (unsigned short)f2h(s));
    r_targ[i] = s;
  }
  // noise L1 over float4-packed elements (98304 of them < 131072 threads)
  float sn = 0.f;
  if (i < NOISE_V4) {
    float4 pa = na[i], pb = nb[i];
    sn = fabsf(pa.x-pb.x) + fabsf(pa.y-pb.y) + fabsf(pa.z-pb.z) + fabsf(pa.w-pb.w);
  }
  for (int o = 1; o < 64; o <<= 1) sn += __shfl_xor(sn, o);
  __shared__ float ws4[4];
  int lane = threadIdx.x & 63, wv = threadIdx.x >> 6;
  if (lane == 0) ws4[wv] = sn;
  __syncthreads();
  if (threadIdx.x == 0) part[blockIdx.x] = ws4[0] + ws4[1] + ws4[2] + ws4[3];
}

// ---------------- chamfer main kernel (no LDS staging: refs are L2-resident) ----------------
__global__ __launch_bounds__(256, 4)
void chamfer_kernel(const ushort4* __restrict__ pk_pred,
                    const ushort4* __restrict__ pk_targ,
                    const float* __restrict__ r_pred,
                    const float* __restrict__ r_targ,
                    float* __restrict__ part) {
  __shared__ float wsum[4];

  const int tid  = threadIdx.x;
  const int lane = tid & 63;
  const int wv   = tid >> 6;
  const int col  = lane & 31;

  const int blk  = blockIdx.x;
  const int qblk = blk & (QBLKS - 1);
  const int bd   = blk >> 7;
  const int dir  = bd & 1;
  const int b    = bd >> 1;

  const ushort4* qpk = dir ? pk_targ : pk_pred;
  const float*   qr  = dir ? r_targ  : r_pred;
  const ushort4* ref = dir ? pk_pred : pk_targ;
  qpk += b * NPTS; qr += b * NPTS; ref += b * NPTS;

  // ---- 4 B fragments (queries), built once. B[k][n]: lane l holds
  // k = 8*(l>>5) + e (e=0..7, reg r packs e=2r,2r+1), n = l&31.
  // Variant v is nonzero only at k = 4v..4v+3 = the query [-2x,-2y,-2z,1].
  const int q = qblk * QPB + wv * 32 + col;
  ushort4 qt = qpk[q];                       // both halves load their column's query
  unsigned int nx = f2h(-2.f * h2f(qt.x));
  unsigned int ny = f2h(-2.f * h2f(qt.y));
  unsigned int nz = f2h(-2.f * h2f(qt.z));
  unsigned int lo = (ny << 16) | nx;
  unsigned int hi = (0x3C00u << 16) | nz;    // [nz, 1.0f16]
  const bool hh = (lane >= 32);

  union BF { halfx8 v; unsigned int u[4]; };
  BF fb0, fb1, fb2, fb3;
  fb0.u[0] = hh ? 0u : lo; fb0.u[1] = hh ? 0u : hi; fb0.u[2] = 0u;           fb0.u[3] = 0u;
  fb1.u[0] = 0u;           fb1.u[1] = 0u;           fb1.u[2] = hh ? 0u : lo; fb1.u[3] = hh ? 0u : hi;
  fb2.u[0] = hh ? lo : 0u; fb2.u[1] = hh ? hi : 0u; fb2.u[2] = 0u;           fb2.u[3] = 0u;
  fb3.u[0] = 0u;           fb3.u[1] = 0u;           fb3.u[2] = hh ? lo : 0u; fb3.u[3] = hh ? hi : 0u;

  f32x16 czero = {0.f,0.f,0.f,0.f, 0.f,0.f,0.f,0.f, 0.f,0.f,0.f,0.f, 0.f,0.f,0.f,0.f};

  union AF { intx4 i; halfx8 h; };

  // Flat loop over all 16384 refs of this (b,dir): 128 iterations, each a
  // fully-coalesced 1 KB/wave global_load_dwordx4 straight from L2.
  // Liveness discipline (round-1 spill post-mortem): ONE d live per MFMA,
  // reduced immediately into 4 independent accumulators (ILP without
  // holding 4x f32x16); unroll capped at 2.
  const char* rbase = (const char*)ref + lane * 16;
  float m0 = 1e30f, m1 = 1e30f, m2 = 1e30f, m3 = 1e30f;

#define RED16(d, acc)                                        \
  {                                                          \
    float t0 = min3((d)[0],  (d)[1],  (d)[2]);               \
    float t1 = min3((d)[3],  (d)[4],  (d)[5]);               \
    float t2 = min3((d)[6],  (d)[7],  (d)[8]);               \
    float t3 = min3((d)[9],  (d)[10], (d)[11]);               \
    float t4 = min3((d)[12], (d)[13], (d)[14]);               \
    float u0 = min3(t0, t1, t2);                             \
    float u1 = min3(t3, t4, (d)[15]);                        \
    acc = min3(acc, u0, u1);                                 \
  }

#pragma unroll 2
  for (int it = 0; it < REF_ITERS; ++it) {
    AF fa;
    fa.i = *(const intx4*)(rbase + (size_t)it * 1024);
    {
      f32x16 d = __builtin_amdgcn_mfma_f32_32x32x16_f16(fa.h, fb0.v, czero, 0, 0, 0);
      RED16(d, m0);
    }
    {
      f32x16 d = __builtin_amdgcn_mfma_f32_32x32x16_f16(fa.h, fb1.v, czero, 0, 0, 0);
      RED16(d, m1);
    }
    {
      f32x16 d = __builtin_amdgcn_mfma_f32_32x32x16_f16(fa.h, fb2.v, czero, 0, 0, 0);
      RED16(d, m2);
    }
    {
      f32x16 d = __builtin_amdgcn_mfma_f32_32x32x16_f16(fa.h, fb3.v, czero, 0, 0, 0);
      RED16(d, m3);
    }
  }
#undef RED16

  float m = fminf(fminf(m0, m1), fminf(m2, m3));

  // lanes l and l^32 cover complementary rows for the same query column
  m = fminf(m, __shfl_xor(m, 32));
  float rq = qr[q];
  float dmin = fmaxf(rq + m, 0.f);
  float v = (lane < 32) ? dmin : 0.f;
  for (int o = 1; o < 32; o <<= 1) v += __shfl_xor(v, o);
  if (lane == 0) wsum[wv] = v;
  __syncthreads();
  if (tid == 0) part[blockIdx.x] = wsum[0] + wsum[1] + wsum[2] + wsum[3];
}

// ---------------- final reduce ----------------
__global__ void final_kernel(const float* __restrict__ part_noise,
                             const float* __restrict__ part_cham,
                             float* __restrict__ out) {
  __shared__ float red[256];
  float s = 0.f;
  for (int i = threadIdx.x; i < PACK_BLOCKS; i += 256) s += part_noise[i];
  float t = 0.f;
  for (int i = threadIdx.x; i < CHAM_BLOCKS; i += 256) t += part_cham[i];
  red[threadIdx.x] = s; __syncthreads();
  for (int o = 128; o; o >>= 1) { if (threadIdx.x < o) red[threadIdx.x] += red[threadIdx.x + o]; __syncthreads(); }
  float noise_sum = red[0];
  __syncthreads();
  red[threadIdx.x] = t; __syncthreads();
  for (int o = 128; o; o >>= 1) { if (threadIdx.x < o) red[threadIdx.x] += red[threadIdx.x + o]; __syncthreads(); }
  if (threadIdx.x == 0)
    out[0] = noise_sum * (1.f / NOISE_N) + 0.1f * red[0] * (1.f / NPTS_TOT);
}

extern "C" void kernel_launch(void* const* d_in, const int* in_sizes, int n_in,
                              void* d_out, int out_size, void* d_ws, size_t ws_size,
                              hipStream_t stream) {
  const float* pn = (const float*)d_in[0];
  const float* an = (const float*)d_in[1];
  const float* pp = (const float*)d_in[2];
  const float* tp = (const float*)d_in[3];

  char* ws = (char*)d_ws;
  float*   noise_part = (float*)(ws + WS_NOISE_PART);
  float*   cham_part  = (float*)(ws + WS_CHAM_PART);
  ushort4* pk_pred    = (ushort4*)(ws + WS_PK_PRED);
  ushort4* pk_targ    = (ushort4*)(ws + WS_PK_TARG);
  float*   r_pred     = (float*)(ws + WS_R_PRED);
  float*   r_targ     = (float*)(ws + WS_R_TARG);

  pack_noise_kernel<<<PACK_BLOCKS, 256, 0, stream>>>(pp, tp, (const float4*)pn, (const float4*)an,
                                                     pk_pred, pk_targ, r_pred, r_targ, noise_part);
  chamfer_kernel<<<CHAM_BLOCKS, 256, 0, stream>>>(pk_pred, pk_targ, r_pred, r_targ, cham_part);
  final_kernel<<<1, 256, 0, stream>>>(noise_part, cham_part, (float*)d_out);
}

// Round 3
// 166.091 us; speedup vs baseline: 1.5858x; 1.0799x over previous
//
#include <hip/hip_runtime.h>
#include <stdint.h>

#define NPTS        16384
#define BATCH       8
#define QPB         128                     // queries per block (4 waves * 32)
#define QBLKS       (NPTS / QPB)            // 128
#define CHAM_BLOCKS (BATCH * 2 * QBLKS)     // 2048
#define NOISE_N     (BATCH * NPTS * 3)      // 393216
#define NOISE_V4    (NOISE_N / 4)           // 98304
#define NPTS_TOT    (BATCH * NPTS)          // 131072
#define PACK_BLOCKS (NPTS_TOT / 256)        // 512
#define REF_ITERS   (NPTS * 8 / 1024)       // 128 (1 KB of packed refs per iter)

// workspace layout (bytes)
#define WS_NOISE_PART 0                     // 512 floats
#define WS_CHAM_PART  4096                  // 2048 floats
#define WS_PK_PRED    16384
#define WS_PK_TARG    (WS_PK_PRED + 8 * NPTS_TOT)
#define WS_R_PRED     (WS_PK_TARG + 8 * NPTS_TOT)
#define WS_R_TARG     (WS_R_PRED + 4 * NPTS_TOT)

using halfx4 = __attribute__((ext_vector_type(4))) _Float16;
using f32x16 = __attribute__((ext_vector_type(16))) float;
using intx4  = __attribute__((ext_vector_type(4))) int;

__device__ __forceinline__ unsigned int f2h(float f) {
  union { _Float16 h; unsigned short s; } v; v.h = (_Float16)f; return v.s;
}
__device__ __forceinline__ float h2f(unsigned short s) {
  union { _Float16 h; unsigned short u; } v; v.u = s; return (float)v.h;
}
__device__ __forceinline__ float min3(float a, float b, float c) {
  return fminf(fminf(a, b), c);   // pattern-matched to v_min3_f32
}

// ---------------- fused pack (f32 xyz -> f16 {x,y,z,s} + f32 r) + noise L1 ----------------
__global__ void pack_noise_kernel(const float* __restrict__ pred,
                                  const float* __restrict__ targ,
                                  const float4* __restrict__ na,
                                  const float4* __restrict__ nb,
                                  ushort4* __restrict__ pk_pred,
                                  ushort4* __restrict__ pk_targ,
                                  float* __restrict__ r_pred,
                                  float* __restrict__ r_targ,
                                  float* __restrict__ part) {
  int i = blockIdx.x * 256 + threadIdx.x;
  {
    float x = pred[3*i+0], y = pred[3*i+1], z = pred[3*i+2];
    float s = __builtin_fmaf(x, x, __builtin_fmaf(y, y, z*z));
    pk_pred[i] = make_ushort4((unsigned short)f2h(x), (unsigned short)f2h(y),
                              (unsigned short)f2h(z), (unsigned short)f2h(s));
    r_pred[i] = s;
  }
  {
    float x = targ[3*i+0], y = targ[3*i+1], z = targ[3*i+2];
    float s = __builtin_fmaf(x, x, __builtin_fmaf(y, y, z*z));
    pk_targ[i] = make_ushort4((unsigned short)f2h(x), (unsigned short)f2h(y),
                              (unsigned short)f2h(z), (unsigned short)f2h(s));
    r_targ[i] = s;
  }
  // noise L1 over float4-packed elements (98304 of them < 131072 threads)
  float sn = 0.f;
  if (i < NOISE_V4) {
    float4 pa = na[i], pb = nb[i];
    sn = fabsf(pa.x-pb.x) + fabsf(pa.y-pb.y) + fabsf(pa.z-pb.z) + fabsf(pa.w-pb.w);
  }
  for (int o = 1; o < 64; o <<= 1) sn += __shfl_xor(sn, o);
  __shared__ float ws4[4];
  int lane = threadIdx.x & 63, wv = threadIdx.x >> 6;
  if (lane == 0) ws4[wv] = sn;
  __syncthreads();
  if (threadIdx.x == 0) part[blockIdx.x] = ws4[0] + ws4[1] + ws4[2] + ws4[3];
}

// ---------------- chamfer main kernel ----------------
// 32x32x8 f16 MFMA: K=8 holds TWO packed ref slots {x,y,z,s}; only 2
// zero-padded B variants needed -> 50% useful MAC density (vs 25% with
// 32x32x16 + 4 variants). Refs read straight from L2 (no LDS staging).
__global__ __launch_bounds__(256, 6)
void chamfer_kernel(const ushort4* __restrict__ pk_pred,
                    const ushort4* __restrict__ pk_targ,
                    const float* __restrict__ r_pred,
                    const float* __restrict__ r_targ,
                    float* __restrict__ part) {
  __shared__ float wsum[4];

  const int tid  = threadIdx.x;
  const int lane = tid & 63;
  const int wv   = tid >> 6;
  const int col  = lane & 31;

  const int blk  = blockIdx.x;
  const int qblk = blk & (QBLKS - 1);
  const int bd   = blk >> 7;
  const int dir  = bd & 1;
  const int b    = bd >> 1;

  const ushort4* qpk = dir ? pk_targ : pk_pred;
  const float*   qr  = dir ? r_targ  : r_pred;
  const ushort4* ref = dir ? pk_pred : pk_targ;
  qpk += b * NPTS; qr += b * NPTS; ref += b * NPTS;

  // ---- B fragments (queries). 32x32x8: B[k][col], lane l holds col=l&31,
  // k = 4*(l>>5)+e (e=0..3, reg r packs e=2r,2r+1). Variant 0 is nonzero at
  // k=0..3 (lanes <32 hold the query [-2x,-2y,-2z,1]); variant 1 at k=4..7.
  const int q = qblk * QPB + wv * 32 + col;
  ushort4 qt = qpk[q];                       // both halves load their column's query
  unsigned int nx = f2h(-2.f * h2f(qt.x));
  unsigned int ny = f2h(-2.f * h2f(qt.y));
  unsigned int nz = f2h(-2.f * h2f(qt.z));
  unsigned int lo = (ny << 16) | nx;
  unsigned int hi = (0x3C00u << 16) | nz;    // [nz, 1.0f16]
  const bool hh = (lane >= 32);

  union BF { halfx4 v; unsigned int u[2]; };
  BF fb0, fb1;
  fb0.u[0] = hh ? 0u : lo; fb0.u[1] = hh ? 0u : hi;
  fb1.u[0] = hh ? lo : 0u; fb1.u[1] = hh ? hi : 0u;

  f32x16 czero = {0.f,0.f,0.f,0.f, 0.f,0.f,0.f,0.f, 0.f,0.f,0.f,0.f, 0.f,0.f,0.f,0.f};

  // A fragments (refs): lane l holds row=l&31, k=4*(l>>5)+e -> one packed
  // ref per halfx4. The 16B/lane load covers 2 refs = 2 A fragments; with
  // 2 B variants each, the 4 MFMA cover all 128 refs of the 1 KB line.
  union AF { intx4 i; halfx4 h[2]; };

  const char* rbase = (const char*)ref + lane * 16;
  float m0 = 1e30f, m1 = 1e30f, m2 = 1e30f, m3 = 1e30f;

#define RED16(d, acc)                                        \
  {                                                          \
    float t0 = min3((d)[0],  (d)[1],  (d)[2]);               \
    float t1 = min3((d)[3],  (d)[4],  (d)[5]);               \
    float t2 = min3((d)[6],  (d)[7],  (d)[8]);               \
    float t3 = min3((d)[9],  (d)[10], (d)[11]);               \
    float t4 = min3((d)[12], (d)[13], (d)[14]);               \
    float u0 = min3(t0, t1, t2);                             \
    float u1 = min3(t3, t4, (d)[15]);                        \
    acc = min3(acc, u0, u1);                                 \
  }

#pragma unroll 2
  for (int it = 0; it < REF_ITERS; ++it) {
    AF fa;
    fa.i = *(const intx4*)(rbase + (size_t)it * 1024);
    {
      f32x16 d = __builtin_amdgcn_mfma_f32_32x32x8f16(fa.h[0], fb0.v, czero, 0, 0, 0);
      RED16(d, m0);
    }
    {
      f32x16 d = __builtin_amdgcn_mfma_f32_32x32x8f16(fa.h[0], fb1.v, czero, 0, 0, 0);
      RED16(d, m1);
    }
    {
      f32x16 d = __builtin_amdgcn_mfma_f32_32x32x8f16(fa.h[1], fb0.v, czero, 0, 0, 0);
      RED16(d, m2);
    }
    {
      f32x16 d = __builtin_amdgcn_mfma_f32_32x32x8f16(fa.h[1], fb1.v, czero, 0, 0, 0);
      RED16(d, m3);
    }
  }
#undef RED16

  float m = fminf(fminf(m0, m1), fminf(m2, m3));

  // lanes l and l^32 cover complementary rows for the same query column
  m = fminf(m, __shfl_xor(m, 32));
  float rq = qr[q];
  float dmin = fmaxf(rq + m, 0.f);
  float v = (lane < 32) ? dmin : 0.f;
  for (int o = 1; o < 32; o <<= 1) v += __shfl_xor(v, o);
  if (lane == 0) wsum[wv] = v;
  __syncthreads();
  if (tid == 0) part[blockIdx.x] = wsum[0] + wsum[1] + wsum[2] + wsum[3];
}

// ---------------- final reduce ----------------
__global__ void final_kernel(const float* __restrict__ part_noise,
                             const float* __restrict__ part_cham,
                             float* __restrict__ out) {
  __shared__ float red[256];
  float s = 0.f;
  for (int i = threadIdx.x; i < PACK_BLOCKS; i += 256) s += part_noise[i];
  float t = 0.f;
  for (int i = threadIdx.x; i < CHAM_BLOCKS; i += 256) t += part_cham[i];
  red[threadIdx.x] = s; __syncthreads();
  for (int o = 128; o; o >>= 1) { if (threadIdx.x < o) red[threadIdx.x] += red[threadIdx.x + o]; __syncthreads(); }
  float noise_sum = red[0];
  __syncthreads();
  red[threadIdx.x] = t; __syncthreads();
  for (int o = 128; o; o >>= 1) { if (threadIdx.x < o) red[threadIdx.x] += red[threadIdx.x + o]; __syncthreads(); }
  if (threadIdx.x == 0)
    out[0] = noise_sum * (1.f / NOISE_N) + 0.1f * red[0] * (1.f / NPTS_TOT);
}

extern "C" void kernel_launch(void* const* d_in, const int* in_sizes, int n_in,
                              void* d_out, int out_size, void* d_ws, size_t ws_size,
                              hipStream_t stream) {
  const float* pn = (const float*)d_in[0];
  const float* an = (const float*)d_in[1];
  const float* pp = (const float*)d_in[2];
  const float* tp = (const float*)d_in[3];

  char* ws = (char*)d_ws;
  float*   noise_part = (float*)(ws + WS_NOISE_PART);
  float*   cham_part  = (float*)(ws + WS_CHAM_PART);
  ushort4* pk_pred    = (ushort4*)(ws + WS_PK_PRED);
  ushort4* pk_targ    = (ushort4*)(ws + WS_PK_TARG);
  float*   r_pred     = (float*)(ws + WS_R_PRED);
  float*   r_targ     = (float*)(ws + WS_R_TARG);

  pack_noise_kernel<<<PACK_BLOCKS, 256, 0, stream>>>(pp, tp, (const float4*)pn, (const float4*)an,
                                                     pk_pred, pk_targ, r_pred, r_targ, noise_part);
  chamfer_kernel<<<CHAM_BLOCKS, 256, 0, stream>>>(pk_pred, pk_targ, r_pred, r_targ, cham_part);
  final_kernel<<<1, 256, 0, stream>>>(noise_part, cham_part, (float*)d_out);
}